// Round 4
// baseline (453.591 us; speedup 1.0000x reference)
//
#include <hip/hip_runtime.h>
#include <hip/hip_bf16.h>

typedef unsigned short u16;
typedef unsigned int u32;
typedef short bf16x8 __attribute__((ext_vector_type(8)));
typedef short s16x2 __attribute__((ext_vector_type(2)));
typedef float f32x4 __attribute__((ext_vector_type(4)));

#define EPSV 1e-5f
// ws byte layout
#define WS_A3    0                       // 128*8 f32
#define WS_C3    4096                    // 128 f32
#define WS_WB    4608                    // 128*128 bf16
#define WS_WCAT  37376                   // 128*160 bf16 [wf2 | A1 | bias | 0]
#define WS_Q     78336                   // 33.55 MB bf16 q = A3@x

union U4 { uint4 q; bf16x8 v; };
union UZ { u32 u; s16x2 s; };

__device__ __forceinline__ u16 f2bf(float f) {
    union { __hip_bfloat16 h; u16 u; } cv;
    cv.h = __float2bfloat16(f);
    return cv.u;
}
__device__ __forceinline__ u32 pack_rne(float a, float b) {
    u32 ua = __float_as_uint(a), ub = __float_as_uint(b);
    ua = ua + 0x7FFFu + ((ua >> 16) & 1u);
    ub = ub + 0x7FFFu + ((ub >> 16) & 1u);
    return (ua >> 16) | (ub & 0xFFFF0000u);
}
// z = relu( bf(qn) + (c3 - bf(qc)) ) packed bf16:
// f32 math -> v_cvt_pk_bf16_f32 (RNE) -> packed-i16 relu (exact for bf16)
__device__ __forceinline__ u32 zpairC(u32 qn, u32 qc, float c3lo, float c3hi) {
    float lo = (c3lo - __uint_as_float(qc << 16)) + __uint_as_float(qn << 16);
    float hi = (c3hi - __uint_as_float(qc & 0xFFFF0000u)) + __uint_as_float(qn & 0xFFFF0000u);
    UZ z;
    asm("v_cvt_pk_bf16_f32 %0, %1, %2" : "=v"(z.u) : "v"(lo), "v"(hi));
    z.s = __builtin_elementwise_max(z.s, (s16x2){0, 0});   // v_pk_max_i16
    return z.u;
}

// ---------------- prep: fold constants (fully parallel, LDS-staged) ----------------
__global__ __launch_bounds__(256) void prep_kernel(
    const float* g1, const float* b1, const float* m1, const float* v1,
    const float* w1, const float* c1b,
    const float* g2, const float* b2, const float* m2, const float* v2,
    const float* wA,
    const float* g3, const float* b3, const float* m3, const float* v3,
    const float* wB, const float* wf, const float* bfv,
    float* ws, u16* wBh, u16* Wc)
{
    __shared__ float wfL[16384];     // wf left half, 64 KB
    __shared__ float w1s[1024];
    __shared__ float c1s[128];
    __shared__ float s1[8], be1[8], s2[8], be2[8];
    __shared__ float w1fS[128][8];
    __shared__ float cbS[128];
    int t = threadIdx.x;

    // stage (coalesced, latency-pipelined across 256 threads)
    for (int i = t; i < 16384; i += 256) wfL[i] = wf[((i >> 7) << 8) + (i & 127)];
    for (int i = t; i < 1024; i += 256) w1s[i] = w1[i];
    if (t < 128) c1s[t] = c1b[t];
    if (t < 8) {
        float s = g1[t] * rsqrtf(v1[t] + EPSV); s1[t] = s; be1[t] = b1[t] - m1[t] * s;
        float u = g2[t] * rsqrtf(v2[t] + EPSV); s2[t] = u; be2[t] = b2[t] - m2[t] * u;
    }
    __syncthreads();

    // fold wf_left @ [w1 | c1b]: thread (o, half) does 4 i's (+ cb on half 1)
    {
        int o = t >> 1, half = t & 1;
        float a0 = 0.f, a1 = 0.f, a2 = 0.f, a3 = 0.f, cb = 0.f;
        const float* wro = wfL + o * 128;
        int i0 = half * 4;
        for (int c = 0; c < 128; c++) {
            float f = wro[c];
            const float* wr = w1s + c * 8 + i0;
            a0 += f * wr[0]; a1 += f * wr[1]; a2 += f * wr[2]; a3 += f * wr[3];
            if (half) cb += f * c1s[c];
        }
        w1fS[o][i0] = a0; w1fS[o][i0 + 1] = a1; w1fS[o][i0 + 2] = a2; w1fS[o][i0 + 3] = a3;
        if (half) cbS[o] = cb;
    }
    __syncthreads();

    if (t < 128) {
        int o = t;
        float s3 = g3[o] * rsqrtf(v3[o] + EPSV);
        float be3 = b3[o] - m3[o] * s3;
        float* A3 = ws;
        float* c3 = ws + 1024;
        float csum = 0.f;
        #pragma unroll
        for (int i = 0; i < 8; i++) {
            float w = wA[o * 8 + i];
            A3[o * 8 + i] = s3 * w * s2[i] * s1[i];
            csum += w * be2[i];
        }
        c3[o] = s3 * csum + be3;

        float bs = bfv[o] + cbS[o];
        #pragma unroll
        for (int i = 0; i < 8; i++) {
            float w1f = w1fS[o][i];
            bs += w1f * be1[i];
            Wc[o * 160 + 128 + i] = f2bf(w1f * s1[i]);
        }
        Wc[o * 160 + 136] = f2bf(bs);
        for (int k = 137; k < 160; k++) Wc[o * 160 + k] = 0;
    }
    // Wcat wf2 block: 16384 elems, coalesced grid-stride
    for (int j = t; j < 16384; j += 256) {
        int o = j >> 7, c = j & 127;
        Wc[o * 160 + c] = f2bf(wf[o * 256 + 128 + c]);
    }
    // wB cast: 8192 packed u32, coalesced
    {
        u32* wbo = (u32*)wBh;
        for (int j = t; j < 8192; j += 256)
            wbo[j] = pack_rne(wB[2 * j], wB[2 * j + 1]);
    }
}

// ---------------- q = A3 @ x (bf16) --------------------
__global__ __launch_bounds__(256) void q_kernel(const float* __restrict__ x,
                                                const float* __restrict__ ws,
                                                u16* __restrict__ q)
{
    int t = blockIdx.x * 256 + threadIdx.x;
    int pt = t >> 6;
    int o = (t & 63) * 2;
    int b = pt >> 16, n = pt & 65535;
    const float* A3 = ws;
    float xv[8];
    #pragma unroll
    for (int i = 0; i < 8; i++) xv[i] = x[(((b << 3) + i) << 16) | n];
    float q0 = 0.f, q1 = 0.f;
    #pragma unroll
    for (int i = 0; i < 8; i++) {
        q0 += A3[o * 8 + i] * xv[i];
        q1 += A3[(o + 1) * 8 + i] * xv[i];
    }
    ((u32*)q)[t] = pack_rne(q0, q1);
}

// ---------------- heavy v5: fused edge-conv + combine, zero-qD, XCD swizzle ------
// Block = 256 threads (4 waves), 16 points. As v4 but:
// (1) qD global array deleted: d = c3 - q[center] recomputed in staging from a
//     16-B sequential (L2-hot) center-row load + per-thread c3 in 8 regs.
//     -67 MB global round-trip; zpair 10 VALU/pair (headroom: VALUBusy 38%).
// (2) bijective XCD swizzle bidL=(bid&7)*1024+(bid>>3): consecutive n-tiles on
//     one XCD -> out 64-B half-lines merge in L2 (kills ~39MB write amp) and
//     center/nbr reads gain L2 locality.
#define HSTEP(I, QN, CN, QC, CC)                                              \
    {                                                                         \
        QN = qb[(u32)((idxR << 4) | gp)];                                     \
        CN = qb[cbase + ((((I) + 2) & 15) << 4)];                             \
        idxR = nb0[nvoff + (((I) + 3) & 15)];                                 \
        f32x4 acc0 = {0.f, 0.f, 0.f, 0.f}, acc1 = {0.f, 0.f, 0.f, 0.f};       \
        _Pragma("unroll")                                                     \
        for (int kt = 0; kt < 4; ++kt) {                                      \
            U4 a; a.q = Abuf[(I) & 1][l15][(kt * 4 + quad) ^ (l15 & 7)];      \
            acc0 = __builtin_amdgcn_mfma_f32_16x16x32_bf16(a.v, wBf[0][kt], acc0, 0, 0, 0); \
            acc1 = __builtin_amdgcn_mfma_f32_16x16x32_bf16(a.v, wBf[1][kt], acc1, 0, 0, 0); \
        }                                                                     \
        float m0 = fmaxf(fmaxf(fmaxf(acc0[0], acc0[1]), acc0[2]), acc0[3]);   \
        float m1 = fmaxf(fmaxf(fmaxf(acc1[0], acc1[1]), acc1[2]), acc1[3]);   \
        m0 = fmaxf(m0, __shfl_xor(m0, 16, 64));                               \
        m0 = fmaxf(m0, __shfl_xor(m0, 32, 64));                               \
        m1 = fmaxf(m1, __shfl_xor(m1, 16, 64));                               \
        m1 = fmaxf(m1, __shfl_xor(m1, 32, 64));                               \
        if (l < 32)                                                           \
            NEu16[(I) * 168 + (w << 5) + l] =                                 \
                (u16)((__float_as_uint((quad == 0) ? m0 : m1) + 0x8000u) >> 16); \
        uint4 f;                                                              \
        f.x = zpairC(QC.x, CC.x, c3a0, c3a1);                                 \
        f.y = zpairC(QC.y, CC.y, c3a2, c3a3);                                 \
        f.z = zpairC(QC.z, CC.z, c3a4, c3a5);                                 \
        f.w = zpairC(QC.w, CC.w, c3a6, c3a7);                                 \
        Abuf[((I) + 1) & 1][s][g0] = f;                                       \
        __syncthreads();                                                      \
    }

__global__ __launch_bounds__(256, 6) void heavy_kernel(
    const u16* __restrict__ q, const int* __restrict__ nbr,
    const u16* __restrict__ wBh, const u16* __restrict__ Wcat,
    const float* __restrict__ x, const float* __restrict__ c3f,
    float* __restrict__ out)
{
    __shared__ uint4 Abuf[2][16][16];      // [buf][slot][granule^swz], 8KB
    __shared__ uint4 NExq[16 * 21];        // [pt][NE(128)|x(8)|1|0...], 5.25KB
    u16* NEu16 = (u16*)NExq;
    const uint4* qv = (const uint4*)q;
    int t = threadIdx.x;
    int w = t >> 6;                        // wave id: 32-channel group
    int l = t & 63;
    int quad = l >> 4, l15 = l & 15;

    // persistent wB^T B-fragments for this wave's 32 channels:
    // B[n = w*32 + j*16 + l15][k = kt*32 + quad*8 + jj]
    bf16x8 wBf[2][4];
    #pragma unroll
    for (int j = 0; j < 2; j++)
        #pragma unroll
        for (int kt = 0; kt < 4; kt++) {
            U4 u; u.q = *(const uint4*)(wBh + (w * 32 + j * 16 + l15) * 128 + kt * 32 + quad * 8);
            wBf[j][kt] = u.v;
        }

    // bijective XCD swizzle: consecutive logical tiles stay on one XCD
    int bidL = ((blockIdx.x & 7) << 10) | (blockIdx.x >> 3);
    int pbase = bidL << 4;                 // 16 points per block, batch-aligned
    int b = pbase >> 16;
    int n0 = pbase & 65535;

    // staging mapping: thread stages one uint4 (8 bf16 ch) of one slot
    int s = t >> 4, gp = t & 15;
    int srow = (s < 15) ? s + 1 : 1;       // slot 15 duplicates neighbor row 1
    const int* nb0 = nbr + ((size_t)b << 20);        // + b*16*65536
    int nvoff = (srow << 16) + n0;                   // 32-bit elem offset
    const uint4* qb = qv + ((size_t)b << 20);        // + b*65536 rows *16
    u32 cbase = (u32)((n0 << 4) | gp);               // center row granule base
    int g0 = gp ^ (s & 7);                 // swizzled granule index

    // per-thread c3 for channels gp*8..gp*8+7 (held in 8 regs)
    const float4* c3q = (const float4*)(c3f + (gp << 3));
    float4 cA = c3q[0], cB = c3q[1];
    float c3a0 = cA.x, c3a1 = cA.y, c3a2 = cA.z, c3a3 = cA.w;
    float c3a4 = cB.x, c3a5 = cB.y, c3a6 = cB.z, c3a7 = cB.w;

    // zero NExq pad region (Wcat cols 137..159 are zero, but 0 x NaN = NaN)
    for (int j = t; j < 336; j += 256) NExq[j] = make_uint4(0u, 0u, 0u, 0u);

    // prologue: issue pt0,pt1 loads; idx 2 ahead; stage pt0 -> buf0
    int idxR;
    uint4 qS0, cS0, qS1, cS1;
    {
        int idx0 = nb0[nvoff];
        qS0 = qb[(u32)((idx0 << 4) | gp)];
        cS0 = qb[cbase];
        int idx1 = nb0[nvoff + 1];
        qS1 = qb[(u32)((idx1 << 4) | gp)];
        cS1 = qb[cbase + 16];
        idxR = nb0[nvoff + 2];
        uint4 f;
        f.x = zpairC(qS0.x, cS0.x, c3a0, c3a1);
        f.y = zpairC(qS0.y, cS0.y, c3a2, c3a3);
        f.z = zpairC(qS0.z, cS0.z, c3a4, c3a5);
        f.w = zpairC(qS0.w, cS0.w, c3a6, c3a7);
        Abuf[0][s][g0] = f;
    }
    __syncthreads();

    for (int i = 0; i < 16; i += 2) {
        HSTEP(i,     qS0, cS0, qS1, cS1)   // issue pt i+2 -> S0, consume S1 (pt i+1)
        HSTEP(i + 1, qS1, cS1, qS0, cS0)   // issue pt i+3 -> S1, consume S0 (pt i+2)
    }

    // ---- fused combine epilogue: out = Wcat @ [NE; x_bf16; 1; 0] ----
    if (t < 64) {
        int pt = t >> 2, pr = t & 3;
        float xa = x[((b * 8 + 2 * pr) << 16) + n0 + pt];
        float xb = x[((b * 8 + 2 * pr + 1) << 16) + n0 + pt];
        ((u32*)NExq)[pt * 84 + 64 + pr] = pack_rne(xa, xb);
        if (pr == 0) ((u32*)NExq)[pt * 84 + 68] = 0x3F80u;   // the "1.0" slot
    }
    __syncthreads();

    // Wcat A-fragments: A[m = w*32 + mt*16 + l15][k = kt*32 + quad*8 + j]
    bf16x8 Wcf[2][5];
    #pragma unroll
    for (int mt = 0; mt < 2; mt++)
        #pragma unroll
        for (int kt = 0; kt < 5; kt++) {
            U4 u; u.q = *(const uint4*)(Wcat + (w * 32 + mt * 16 + l15) * 160 + kt * 32 + quad * 8);
            Wcf[mt][kt] = u.v;
        }
    f32x4 oa[2];
    oa[0] = (f32x4){0.f, 0.f, 0.f, 0.f};
    oa[1] = (f32x4){0.f, 0.f, 0.f, 0.f};
    #pragma unroll
    for (int kt = 0; kt < 5; ++kt) {
        U4 u; u.q = NExq[l15 * 21 + kt * 4 + quad];
        oa[0] = __builtin_amdgcn_mfma_f32_16x16x32_bf16(Wcf[0][kt], u.v, oa[0], 0, 0, 0);
        oa[1] = __builtin_amdgcn_mfma_f32_16x16x32_bf16(Wcf[1][kt], u.v, oa[1], 0, 0, 0);
    }
    #pragma unroll
    for (int mt = 0; mt < 2; ++mt) {
        int ob = w * 32 + mt * 16 + quad * 4;
        #pragma unroll
        for (int r = 0; r < 4; ++r)
            out[(((b << 7) + ob + r) << 16) + n0 + l15] = oa[mt][r];
    }
}

extern "C" void kernel_launch(void* const* d_in, const int* in_sizes, int n_in,
                              void* d_out, int out_size, void* d_ws, size_t ws_size,
                              hipStream_t stream) {
    const float* x   = (const float*)d_in[0];
    const int*   nbr = (const int*)d_in[1];
    const float* g1  = (const float*)d_in[2];
    const float* b1  = (const float*)d_in[3];
    const float* m1  = (const float*)d_in[4];
    const float* v1  = (const float*)d_in[5];
    const float* w1  = (const float*)d_in[6];
    const float* c1b = (const float*)d_in[7];
    const float* g2  = (const float*)d_in[8];
    const float* b2  = (const float*)d_in[9];
    const float* m2  = (const float*)d_in[10];
    const float* v2  = (const float*)d_in[11];
    const float* wA  = (const float*)d_in[12];
    const float* g3  = (const float*)d_in[13];
    const float* b3  = (const float*)d_in[14];
    const float* m3  = (const float*)d_in[15];
    const float* v3  = (const float*)d_in[16];
    const float* wB  = (const float*)d_in[17];
    const float* wf  = (const float*)d_in[18];
    const float* bfv = (const float*)d_in[19];

    float* wsF  = (float*)d_ws;
    u16*   wBh  = (u16*)((char*)d_ws + WS_WB);
    u16*   Wcat = (u16*)((char*)d_ws + WS_WCAT);
    u16*   q    = (u16*)((char*)d_ws + WS_Q);
    float* c3f  = (float*)((char*)d_ws + WS_C3);
    float* out  = (float*)d_out;

    prep_kernel<<<1, 256, 0, stream>>>(g1, b1, m1, v1, w1, c1b, g2, b2, m2, v2,
                                       wA, g3, b3, m3, v3, wB, wf, bfv, wsF, wBh, Wcat);
    q_kernel<<<32768, 256, 0, stream>>>(x, wsF, q);
    heavy_kernel<<<8192, 256, 0, stream>>>(q, nbr, wBh, Wcat, x, c3f, out);
}

// Round 6
// 252.314 us; speedup vs baseline: 1.7977x; 1.7977x over previous
//
#include <hip/hip_runtime.h>
#include <hip/hip_bf16.h>

typedef unsigned short u16;
typedef unsigned int u32;
typedef short bf16x8 __attribute__((ext_vector_type(8)));
typedef float f32x4 __attribute__((ext_vector_type(4)));

#define EPSV 1e-5f
// ws byte layout
#define WS_A3L   0                       // 128*32 bf16 [A3 | c3 | 0...] = 8 KB
#define WS_WB    8192                    // 128*128 bf16 = 32 KB
#define WS_WCAT  40960                   // 128*160 bf16 [wf2 | A1 | bias | 0] = 40 KB
#define WS_XH    81920                   // 2*65536*8 f32 x-transpose = 4 MB

union U4 { uint4 q; bf16x8 v; };

__device__ __forceinline__ u16 f2bf(float f) {
    union { __hip_bfloat16 h; u16 u; } cv;
    cv.h = __float2bfloat16(f);
    return cv.u;
}
// RNE pack of two f32 into packed bf16 pair (lo = a, hi = b) — pure integer ops
__device__ __forceinline__ u32 pack_rne(float a, float b) {
    u32 ua = __float_as_uint(a), ub = __float_as_uint(b);
    ua = ua + 0x7FFFu + ((ua >> 16) & 1u);
    ub = ub + 0x7FFFu + ((ub >> 16) & 1u);
    return (ua >> 16) | (ub & 0xFFFF0000u);
}

// ---------------- prep: fold constants (fully parallel, LDS-staged) ----------------
__global__ __launch_bounds__(256) void prep_kernel(
    const float* g1, const float* b1, const float* m1, const float* v1,
    const float* w1, const float* c1b,
    const float* g2, const float* b2, const float* m2, const float* v2,
    const float* wA,
    const float* g3, const float* b3, const float* m3, const float* v3,
    const float* wB, const float* wf, const float* bfv,
    u16* A3L, u16* wBh, u16* Wc)
{
    __shared__ float wfL[16384];     // wf left half, 64 KB
    __shared__ float w1s[1024];
    __shared__ float c1s[128];
    __shared__ float s1[8], be1[8], s2[8], be2[8];
    __shared__ float w1fS[128][8];
    __shared__ float cbS[128];
    int t = threadIdx.x;

    for (int i = t; i < 16384; i += 256) wfL[i] = wf[((i >> 7) << 8) + (i & 127)];
    for (int i = t; i < 1024; i += 256) w1s[i] = w1[i];
    if (t < 128) c1s[t] = c1b[t];
    if (t < 8) {
        float s = g1[t] * rsqrtf(v1[t] + EPSV); s1[t] = s; be1[t] = b1[t] - m1[t] * s;
        float u = g2[t] * rsqrtf(v2[t] + EPSV); s2[t] = u; be2[t] = b2[t] - m2[t] * u;
    }
    __syncthreads();

    // fold wf_left @ [w1 | c1b]: thread (o, half) does 4 i's (+ cb on half 1)
    {
        int o = t >> 1, half = t & 1;
        float a0 = 0.f, a1 = 0.f, a2 = 0.f, a3 = 0.f, cb = 0.f;
        const float* wro = wfL + o * 128;
        int i0 = half * 4;
        for (int c = 0; c < 128; c++) {
            float f = wro[c];
            const float* wr = w1s + c * 8 + i0;
            a0 += f * wr[0]; a1 += f * wr[1]; a2 += f * wr[2]; a3 += f * wr[3];
            if (half) cb += f * c1s[c];
        }
        w1fS[o][i0] = a0; w1fS[o][i0 + 1] = a1; w1fS[o][i0 + 2] = a2; w1fS[o][i0 + 3] = a3;
        if (half) cbS[o] = cb;
    }
    __syncthreads();

    if (t < 128) {
        int o = t;
        float s3 = g3[o] * rsqrtf(v3[o] + EPSV);
        float be3 = b3[o] - m3[o] * s3;
        float csum = 0.f;
        #pragma unroll
        for (int i = 0; i < 8; i++) {
            float wv = wA[o * 8 + i];
            A3L[o * 32 + i] = f2bf(s3 * wv * s2[i] * s1[i]);
            csum += wv * be2[i];
        }
        A3L[o * 32 + 8] = f2bf(s3 * csum + be3);   // c3 folded as ones-channel
        for (int k = 9; k < 32; k++) A3L[o * 32 + k] = 0;

        float bs = bfv[o] + cbS[o];
        #pragma unroll
        for (int i = 0; i < 8; i++) {
            float w1f = w1fS[o][i];
            bs += w1f * be1[i];
            Wc[o * 160 + 128 + i] = f2bf(w1f * s1[i]);
        }
        Wc[o * 160 + 136] = f2bf(bs);
        for (int k = 137; k < 160; k++) Wc[o * 160 + k] = 0;
    }
    // Wcat wf2 block: 16384 elems, coalesced grid-stride
    for (int j = t; j < 16384; j += 256) {
        int o = j >> 7, c = j & 127;
        Wc[o * 160 + c] = f2bf(wf[o * 256 + 128 + c]);
    }
    // wB cast: 8192 packed u32, coalesced
    {
        u32* wbo = (u32*)wBh;
        for (int j = t; j < 8192; j += 256)
            wbo[j] = pack_rne(wB[2 * j], wB[2 * j + 1]);
    }
}

// ---------------- xhat: x transpose to [b][n][8ch] f32 rows (32B) ----------------
__global__ __launch_bounds__(256) void xhat_kernel(const float* __restrict__ x,
                                                   float* __restrict__ xh)
{
    int t = blockIdx.x * 256 + threadIdx.x;   // 131072 threads
    int b = t >> 16, n = t & 65535;
    float4 a, c;
    a.x = x[(((b << 3) + 0) << 16) | n];
    a.y = x[(((b << 3) + 1) << 16) | n];
    a.z = x[(((b << 3) + 2) << 16) | n];
    a.w = x[(((b << 3) + 3) << 16) | n];
    c.x = x[(((b << 3) + 4) << 16) | n];
    c.y = x[(((b << 3) + 5) << 16) | n];
    c.z = x[(((b << 3) + 6) << 16) | n];
    c.w = x[(((b << 3) + 7) << 16) | n];
    float4* o = (float4*)xh + ((size_t)t << 1);
    o[0] = a; o[1] = c;
}

// ---------------- heavy v7: x-gather (L2-resident), 2-stage MFMA, fused combine ---
// = R5's v6 structure with the risky parts made boring:
//  * NO inline asm anywhere: all bf16 packing via pack_rne (integer, proven R0+),
//    relu via f32 fmaxf before packing (exact: relu/round commute at 0).
//  * DX rows padded to stride 5 uint4 -> S1's ds_read_b128 banks spread.
// Phase A: 256 threads gather one (pt,slot) x-row (32B f32; working set 4MB/batch
//   -> L2-resident; the 256B q-row gather and its ~2.5TB/s fabric wall are gone),
//   dx = xg - xc in f32, pack bf16 -> DX row [dx(8) | 1,0.. | 0 | 0] (ones ch
//   multiplies the folded c3 in stage-1). ch16-31 zeroed (0*garbage = NaN guard).
// Stage-1 (per pt): Z^T[o x slot] = A3L @ DX^T. Wave w computes o-blocks
//   32w..32w+15 (mi=0) and 32w+16..+31 (mi=1): lane(quad,l15) gets z[o = 32w +
//   16mi + 4q + r][slot = l15] -> relu+pack -> channel c at Abuf[slot][granule
//   (c>>3)^(slot&7)], exactly the layout S2 reads (granule coverage: gA/gB x
//   half(quad&1) tiles each slot row exactly once).
// Stage-2 (per pt): proven R2 core: 4x ds_read_b128 + 8 MFMA + max-reduce ->
//   NE u16 into NExq LDS. Fused combine epilogue (proven R3/R4) writes out.
#define S1(P, BUF)                                                            \
    {                                                                         \
        U4 bfr; bfr.q = DX[(((P) << 4) + l15) * 5 + quad];                    \
        f32x4 z0 = {0.f, 0.f, 0.f, 0.f}, z1 = {0.f, 0.f, 0.f, 0.f};           \
        z0 = __builtin_amdgcn_mfma_f32_16x16x32_bf16(a3f[0], bfr.v, z0, 0, 0, 0); \
        z1 = __builtin_amdgcn_mfma_f32_16x16x32_bf16(a3f[1], bfr.v, z1, 0, 0, 0); \
        u32 w00 = pack_rne(fmaxf(z0[0], 0.f), fmaxf(z0[1], 0.f));             \
        u32 w01 = pack_rne(fmaxf(z0[2], 0.f), fmaxf(z0[3], 0.f));             \
        u32 w10 = pack_rne(fmaxf(z1[0], 0.f), fmaxf(z1[1], 0.f));             \
        u32 w11 = pack_rne(fmaxf(z1[2], 0.f), fmaxf(z1[3], 0.f));             \
        u32* ab = (u32*)Abuf + (BUF) * 1024 + (l15 << 6) + ((quad & 1) << 1); \
        int gA = ((w << 2) + (quad >> 1)) ^ (l15 & 7);                        \
        int gB = ((w << 2) + 2 + (quad >> 1)) ^ (l15 & 7);                    \
        *(uint2*)(ab + (gA << 2)) = make_uint2(w00, w01);                     \
        *(uint2*)(ab + (gB << 2)) = make_uint2(w10, w11);                     \
    }

#define S2(P, BUF)                                                            \
    {                                                                         \
        f32x4 acc0 = {0.f, 0.f, 0.f, 0.f}, acc1 = {0.f, 0.f, 0.f, 0.f};       \
        _Pragma("unroll")                                                     \
        for (int kt = 0; kt < 4; ++kt) {                                      \
            U4 a; a.q = Abuf[BUF][l15][((kt << 2) + quad) ^ (l15 & 7)];       \
            acc0 = __builtin_amdgcn_mfma_f32_16x16x32_bf16(a.v, wBf[0][kt], acc0, 0, 0, 0); \
            acc1 = __builtin_amdgcn_mfma_f32_16x16x32_bf16(a.v, wBf[1][kt], acc1, 0, 0, 0); \
        }                                                                     \
        float m0 = fmaxf(fmaxf(fmaxf(acc0[0], acc0[1]), acc0[2]), acc0[3]);   \
        float m1 = fmaxf(fmaxf(fmaxf(acc1[0], acc1[1]), acc1[2]), acc1[3]);   \
        m0 = fmaxf(m0, __shfl_xor(m0, 16, 64));                               \
        m0 = fmaxf(m0, __shfl_xor(m0, 32, 64));                               \
        m1 = fmaxf(m1, __shfl_xor(m1, 16, 64));                               \
        m1 = fmaxf(m1, __shfl_xor(m1, 32, 64));                               \
        if (l < 32)                                                           \
            NEu16[(P) * 168 + (w << 5) + l] =                                 \
                (u16)((__float_as_uint((quad == 0) ? m0 : m1) + 0x8000u) >> 16); \
    }

__global__ __launch_bounds__(256, 4) void heavy_kernel(
    const float* __restrict__ xh, const int* __restrict__ nbr,
    const u16* __restrict__ A3Lg, const u16* __restrict__ wBh,
    const u16* __restrict__ Wcat, const float* __restrict__ x,
    float* __restrict__ out)
{
    __shared__ uint4 DX[256 * 5];          // [row][dx|ones|0|0|pad], 20KB (pad: banks)
    __shared__ uint4 Abuf[2][16][16];      // z dbuf [buf][slot][granule^swz], 8KB
    __shared__ uint4 NExq[16 * 21];        // [pt][NE(128)|x(8)|1|0...], 5.25KB
    u16* NEu16 = (u16*)NExq;
    int t = threadIdx.x;
    int w = t >> 6, l = t & 63;
    int quad = l >> 4, l15 = l & 15;

    // persistent wB^T B-fragments (stage-2), 32 regs
    bf16x8 wBf[2][4];
    #pragma unroll
    for (int j = 0; j < 2; j++)
        #pragma unroll
        for (int kt = 0; kt < 4; kt++) {
            U4 u; u.q = *(const uint4*)(wBh + (w * 32 + j * 16 + l15) * 128 + kt * 32 + quad * 8);
            wBf[j][kt] = u.v;
        }
    // persistent stage-1 A-frags: A3L rows for o-blocks 32w+16mi, 16 regs
    bf16x8 a3f[2];
    #pragma unroll
    for (int mi = 0; mi < 2; mi++) {
        U4 u; u.q = *(const uint4*)(A3Lg + (((2 * w + mi) * 16 + l15) << 5) + quad * 8);
        a3f[mi] = u.v;
    }

    int pbase = blockIdx.x << 4;           // 16 points per block, batch-aligned
    int b = pbase >> 16;
    int n0 = pbase & 65535;

    // zero NExq pad region (Wcat cols 137..159 are zero, but 0 x NaN = NaN)
    for (int j = t; j < 336; j += 256) NExq[j] = make_uint4(0u, 0u, 0u, 0u);

    // ---- phase A: gather all 256 Delta-rows ----
    {
        int pt = t >> 4, slot = t & 15;
        int srow = (slot < 15) ? slot + 1 : 1;     // slot 15 dups neighbor row 1
        int idx = nbr[(b << 20) | (srow << 16) | (n0 + pt)];
        const float4* xq = (const float4*)xh + ((size_t)b << 17);
        float4 ga = xq[(u32)(idx << 1)], gb = xq[(u32)((idx << 1) + 1)];
        float4 ca = xq[(u32)((n0 + pt) << 1)], cb = xq[(u32)(((n0 + pt) << 1) + 1)];
        uint4 d;
        d.x = pack_rne(ga.x - ca.x, ga.y - ca.y);
        d.y = pack_rne(ga.z - ca.z, ga.w - ca.w);
        d.z = pack_rne(gb.x - cb.x, gb.y - cb.y);
        d.w = pack_rne(gb.z - cb.z, gb.w - cb.w);
        DX[t * 5 + 0] = d;
        DX[t * 5 + 1] = make_uint4(0x00003F80u, 0u, 0u, 0u);   // ones-channel (ch8)
        DX[t * 5 + 2] = make_uint4(0u, 0u, 0u, 0u);            // ch16-31 = 0 (NaN guard)
        DX[t * 5 + 3] = make_uint4(0u, 0u, 0u, 0u);
    }
    __syncthreads();

    S1(0, 0)
    __syncthreads();

    for (int p = 0; p < 16; p += 2) {
        S1(p + 1, 1)
        S2(p, 0)
        __syncthreads();
        if (p < 14) S1(p + 2, 0)
        S2(p + 1, 1)
        __syncthreads();
    }

    // ---- fused combine epilogue: out = Wcat @ [NE; x_bf16; 1; 0] ----
    if (t < 64) {
        int pt = t >> 2, pr = t & 3;
        float xa = x[((b * 8 + 2 * pr) << 16) + n0 + pt];
        float xb = x[((b * 8 + 2 * pr + 1) << 16) + n0 + pt];
        ((u32*)NExq)[pt * 84 + 64 + pr] = pack_rne(xa, xb);
        if (pr == 0) ((u32*)NExq)[pt * 84 + 68] = 0x3F80u;   // the "1.0" slot
    }
    __syncthreads();

    bf16x8 Wcf[2][5];
    #pragma unroll
    for (int mt = 0; mt < 2; mt++)
        #pragma unroll
        for (int kt = 0; kt < 5; kt++) {
            U4 u; u.q = *(const uint4*)(Wcat + (w * 32 + mt * 16 + l15) * 160 + kt * 32 + quad * 8);
            Wcf[mt][kt] = u.v;
        }
    f32x4 oa[2];
    oa[0] = (f32x4){0.f, 0.f, 0.f, 0.f};
    oa[1] = (f32x4){0.f, 0.f, 0.f, 0.f};
    #pragma unroll
    for (int kt = 0; kt < 5; ++kt) {
        U4 u; u.q = NExq[l15 * 21 + kt * 4 + quad];
        oa[0] = __builtin_amdgcn_mfma_f32_16x16x32_bf16(Wcf[0][kt], u.v, oa[0], 0, 0, 0);
        oa[1] = __builtin_amdgcn_mfma_f32_16x16x32_bf16(Wcf[1][kt], u.v, oa[1], 0, 0, 0);
    }
    #pragma unroll
    for (int mt = 0; mt < 2; ++mt) {
        int ob = w * 32 + mt * 16 + quad * 4;
        #pragma unroll
        for (int r = 0; r < 4; ++r)
            out[(((b << 7) + ob + r) << 16) + n0 + l15] = oa[mt][r];
    }
}

extern "C" void kernel_launch(void* const* d_in, const int* in_sizes, int n_in,
                              void* d_out, int out_size, void* d_ws, size_t ws_size,
                              hipStream_t stream) {
    const float* x   = (const float*)d_in[0];
    const int*   nbr = (const int*)d_in[1];
    const float* g1  = (const float*)d_in[2];
    const float* b1  = (const float*)d_in[3];
    const float* m1  = (const float*)d_in[4];
    const float* v1  = (const float*)d_in[5];
    const float* w1  = (const float*)d_in[6];
    const float* c1b = (const float*)d_in[7];
    const float* g2  = (const float*)d_in[8];
    const float* b2  = (const float*)d_in[9];
    const float* m2  = (const float*)d_in[10];
    const float* v2  = (const float*)d_in[11];
    const float* wA  = (const float*)d_in[12];
    const float* g3  = (const float*)d_in[13];
    const float* b3  = (const float*)d_in[14];
    const float* m3  = (const float*)d_in[15];
    const float* v3  = (const float*)d_in[16];
    const float* wB  = (const float*)d_in[17];
    const float* wf  = (const float*)d_in[18];
    const float* bfv = (const float*)d_in[19];

    u16*   A3L  = (u16*)((char*)d_ws + WS_A3L);
    u16*   wBh  = (u16*)((char*)d_ws + WS_WB);
    u16*   Wcat = (u16*)((char*)d_ws + WS_WCAT);
    float* xh   = (float*)((char*)d_ws + WS_XH);
    float* out  = (float*)d_out;

    prep_kernel<<<1, 256, 0, stream>>>(g1, b1, m1, v1, w1, c1b, g2, b2, m2, v2,
                                       wA, g3, b3, m3, v3, wB, wf, bfv, A3L, wBh, Wcat);
    xhat_kernel<<<512, 256, 0, stream>>>(x, xh);
    heavy_kernel<<<8192, 256, 0, stream>>>(xh, nbr, A3L, wBh, Wcat, x, out);
}

// Round 7
// 243.401 us; speedup vs baseline: 1.8636x; 1.0366x over previous
//
#include <hip/hip_runtime.h>
#include <hip/hip_bf16.h>

typedef unsigned short u16;
typedef unsigned int u32;
typedef short bf16x8 __attribute__((ext_vector_type(8)));
typedef float f32x4 __attribute__((ext_vector_type(4)));

#define EPSV 1e-5f
// ws byte layout
#define WS_A3L   0                       // 128*32 bf16 [A3 | c3 | 0...] = 8 KB
#define WS_WB    8192                    // 128*128 bf16 = 32 KB
#define WS_WCAT  40960                   // 128*160 bf16 [wf2 | A1 | bias | 0] = 40 KB
#define WS_XH    81920                   // 2*65536*8 f32 x-transpose = 4 MB

union U4 { uint4 q; bf16x8 v; };

__device__ __forceinline__ u16 f2bf(float f) {
    union { __hip_bfloat16 h; u16 u; } cv;
    cv.h = __float2bfloat16(f);
    return cv.u;
}
// RNE pack of two f32 into packed bf16 pair (lo = a, hi = b) — pure integer ops
__device__ __forceinline__ u32 pack_rne(float a, float b) {
    u32 ua = __float_as_uint(a), ub = __float_as_uint(b);
    ua = ua + 0x7FFFu + ((ua >> 16) & 1u);
    ub = ub + 0x7FFFu + ((ub >> 16) & 1u);
    return (ua >> 16) | (ub & 0xFFFF0000u);
}

// ---------------- prep: fold constants (fully parallel, LDS-staged) ----------------
__global__ __launch_bounds__(256) void prep_kernel(
    const float* g1, const float* b1, const float* m1, const float* v1,
    const float* w1, const float* c1b,
    const float* g2, const float* b2, const float* m2, const float* v2,
    const float* wA,
    const float* g3, const float* b3, const float* m3, const float* v3,
    const float* wB, const float* wf, const float* bfv,
    u16* A3L, u16* wBh, u16* Wc)
{
    __shared__ float wfL[16384];     // wf left half, 64 KB
    __shared__ float w1s[1024];
    __shared__ float c1s[128];
    __shared__ float s1[8], be1[8], s2[8], be2[8];
    __shared__ float w1fS[128][8];
    __shared__ float cbS[128];
    int t = threadIdx.x;

    for (int i = t; i < 16384; i += 256) wfL[i] = wf[((i >> 7) << 8) + (i & 127)];
    for (int i = t; i < 1024; i += 256) w1s[i] = w1[i];
    if (t < 128) c1s[t] = c1b[t];
    if (t < 8) {
        float s = g1[t] * rsqrtf(v1[t] + EPSV); s1[t] = s; be1[t] = b1[t] - m1[t] * s;
        float u = g2[t] * rsqrtf(v2[t] + EPSV); s2[t] = u; be2[t] = b2[t] - m2[t] * u;
    }
    __syncthreads();

    // fold wf_left @ [w1 | c1b]: thread (o, half) does 4 i's (+ cb on half 1)
    {
        int o = t >> 1, half = t & 1;
        float a0 = 0.f, a1 = 0.f, a2 = 0.f, a3 = 0.f, cb = 0.f;
        const float* wro = wfL + o * 128;
        int i0 = half * 4;
        for (int c = 0; c < 128; c++) {
            float f = wro[c];
            const float* wr = w1s + c * 8 + i0;
            a0 += f * wr[0]; a1 += f * wr[1]; a2 += f * wr[2]; a3 += f * wr[3];
            if (half) cb += f * c1s[c];
        }
        w1fS[o][i0] = a0; w1fS[o][i0 + 1] = a1; w1fS[o][i0 + 2] = a2; w1fS[o][i0 + 3] = a3;
        if (half) cbS[o] = cb;
    }
    __syncthreads();

    if (t < 128) {
        int o = t;
        float s3 = g3[o] * rsqrtf(v3[o] + EPSV);
        float be3 = b3[o] - m3[o] * s3;
        float csum = 0.f;
        #pragma unroll
        for (int i = 0; i < 8; i++) {
            float wv = wA[o * 8 + i];
            A3L[o * 32 + i] = f2bf(s3 * wv * s2[i] * s1[i]);
            csum += wv * be2[i];
        }
        A3L[o * 32 + 8] = f2bf(s3 * csum + be3);   // c3 folded as ones-channel
        for (int k = 9; k < 32; k++) A3L[o * 32 + k] = 0;

        float bs = bfv[o] + cbS[o];
        #pragma unroll
        for (int i = 0; i < 8; i++) {
            float w1f = w1fS[o][i];
            bs += w1f * be1[i];
            Wc[o * 160 + 128 + i] = f2bf(w1f * s1[i]);
        }
        Wc[o * 160 + 136] = f2bf(bs);
        for (int k = 137; k < 160; k++) Wc[o * 160 + k] = 0;
    }
    // Wcat wf2 block: 16384 elems, coalesced grid-stride
    for (int j = t; j < 16384; j += 256) {
        int o = j >> 7, c = j & 127;
        Wc[o * 160 + c] = f2bf(wf[o * 256 + 128 + c]);
    }
    // wB cast: 8192 packed u32, coalesced
    {
        u32* wbo = (u32*)wBh;
        for (int j = t; j < 8192; j += 256)
            wbo[j] = pack_rne(wB[2 * j], wB[2 * j + 1]);
    }
}

// ---------------- xhat: x transpose to [b][n][8ch] f32 rows (32B) ----------------
__global__ __launch_bounds__(256) void xhat_kernel(const float* __restrict__ x,
                                                   float* __restrict__ xh)
{
    int t = blockIdx.x * 256 + threadIdx.x;   // 131072 threads
    int b = t >> 16, n = t & 65535;
    float4 a, c;
    a.x = x[(((b << 3) + 0) << 16) | n];
    a.y = x[(((b << 3) + 1) << 16) | n];
    a.z = x[(((b << 3) + 2) << 16) | n];
    a.w = x[(((b << 3) + 3) << 16) | n];
    c.x = x[(((b << 3) + 4) << 16) | n];
    c.y = x[(((b << 3) + 5) << 16) | n];
    c.z = x[(((b << 3) + 6) << 16) | n];
    c.w = x[(((b << 3) + 7) << 16) | n];
    float4* o = (float4*)xh + ((size_t)t << 1);
    o[0] = a; o[1] = c;
}

// ---------------- heavy v8: v7 + cvtpk S1 pack, slim DX, occupancy 6 ----------
// Changes vs R6 (each counter-directed):
//  * S1 pack via v_cvt_pk_bf16_f32 inline asm (T12-proven pattern): 12 VALU/pt
//    vs 32 (pack_rne). Single-variable test of R5's NaN (relu stays fmaxf-f32,
//    pack_rne kept everywhere off the hot path).
//  * DX = 256 x 16B (4KB, was 20KB): only quad-0 lanes ds_read it (2-way, free);
//    quad1 fragment = constant ones-vector (k=8 multiplies folded c3), quads
//    2/3 = zero. Kills the 8-way stride-5 read + 4/5 of phase-A writes.
//  * launch_bounds(256,6), LDS 17.7KB -> ~6 blocks/CU (occupancy 41->~70%).
//  * epilogue x-pack reads xh (coalesced float4) instead of strided x.
#define S1(P, BUF)                                                            \
    {                                                                         \
        U4 bfr;                                                               \
        if (quad == 0)      bfr.q = DXs[((P) << 4) + l15];                    \
        else if (quad == 1) bfr.q = make_uint4(0x00003F80u, 0u, 0u, 0u);      \
        else                bfr.q = make_uint4(0u, 0u, 0u, 0u);               \
        f32x4 z0 = {0.f, 0.f, 0.f, 0.f}, z1 = {0.f, 0.f, 0.f, 0.f};           \
        z0 = __builtin_amdgcn_mfma_f32_16x16x32_bf16(a3f[0], bfr.v, z0, 0, 0, 0); \
        z1 = __builtin_amdgcn_mfma_f32_16x16x32_bf16(a3f[1], bfr.v, z1, 0, 0, 0); \
        u32 w00, w01, w10, w11;                                               \
        asm("v_cvt_pk_bf16_f32 %0, %1, %2" : "=v"(w00)                        \
            : "v"(fmaxf(z0[0], 0.f)), "v"(fmaxf(z0[1], 0.f)));                \
        asm("v_cvt_pk_bf16_f32 %0, %1, %2" : "=v"(w01)                        \
            : "v"(fmaxf(z0[2], 0.f)), "v"(fmaxf(z0[3], 0.f)));                \
        asm("v_cvt_pk_bf16_f32 %0, %1, %2" : "=v"(w10)                        \
            : "v"(fmaxf(z1[0], 0.f)), "v"(fmaxf(z1[1], 0.f)));                \
        asm("v_cvt_pk_bf16_f32 %0, %1, %2" : "=v"(w11)                        \
            : "v"(fmaxf(z1[2], 0.f)), "v"(fmaxf(z1[3], 0.f)));                \
        u32* ab = (u32*)Abuf + (BUF) * 1024 + (l15 << 6) + ((quad & 1) << 1); \
        int gA = ((w << 2) + (quad >> 1)) ^ (l15 & 7);                        \
        int gB = ((w << 2) + 2 + (quad >> 1)) ^ (l15 & 7);                    \
        *(uint2*)(ab + (gA << 2)) = make_uint2(w00, w01);                     \
        *(uint2*)(ab + (gB << 2)) = make_uint2(w10, w11);                     \
    }

#define S2(P, BUF)                                                            \
    {                                                                         \
        f32x4 acc0 = {0.f, 0.f, 0.f, 0.f}, acc1 = {0.f, 0.f, 0.f, 0.f};       \
        _Pragma("unroll")                                                     \
        for (int kt = 0; kt < 4; ++kt) {                                      \
            U4 a; a.q = Abuf[BUF][l15][((kt << 2) + quad) ^ (l15 & 7)];       \
            acc0 = __builtin_amdgcn_mfma_f32_16x16x32_bf16(a.v, wBf[0][kt], acc0, 0, 0, 0); \
            acc1 = __builtin_amdgcn_mfma_f32_16x16x32_bf16(a.v, wBf[1][kt], acc1, 0, 0, 0); \
        }                                                                     \
        float m0 = fmaxf(fmaxf(fmaxf(acc0[0], acc0[1]), acc0[2]), acc0[3]);   \
        float m1 = fmaxf(fmaxf(fmaxf(acc1[0], acc1[1]), acc1[2]), acc1[3]);   \
        m0 = fmaxf(m0, __shfl_xor(m0, 16, 64));                               \
        m0 = fmaxf(m0, __shfl_xor(m0, 32, 64));                               \
        m1 = fmaxf(m1, __shfl_xor(m1, 16, 64));                               \
        m1 = fmaxf(m1, __shfl_xor(m1, 32, 64));                               \
        if (l < 32)                                                           \
            NEu16[(P) * 168 + (w << 5) + l] =                                 \
                (u16)((__float_as_uint((quad == 0) ? m0 : m1) + 0x8000u) >> 16); \
    }

__global__ __launch_bounds__(256, 6) void heavy_kernel(
    const float* __restrict__ xh, const int* __restrict__ nbr,
    const u16* __restrict__ A3Lg, const u16* __restrict__ wBh,
    const u16* __restrict__ Wcat, float* __restrict__ out)
{
    __shared__ uint4 DXs[256];             // [row] dx bf16x8, 4KB
    __shared__ uint4 Abuf[2][16][16];      // z dbuf [buf][slot][granule^swz], 8KB
    __shared__ uint4 NExq[16 * 21];        // [pt][NE(128)|x(8)|1|0...], 5.25KB
    u16* NEu16 = (u16*)NExq;
    int t = threadIdx.x;
    int w = t >> 6, l = t & 63;
    int quad = l >> 4, l15 = l & 15;

    // persistent wB^T B-fragments (stage-2), 32 regs
    bf16x8 wBf[2][4];
    #pragma unroll
    for (int j = 0; j < 2; j++)
        #pragma unroll
        for (int kt = 0; kt < 4; kt++) {
            U4 u; u.q = *(const uint4*)(wBh + (w * 32 + j * 16 + l15) * 128 + kt * 32 + quad * 8);
            wBf[j][kt] = u.v;
        }
    // persistent stage-1 A-frags: A3L rows for o-blocks 32w+16mi, 16 regs
    bf16x8 a3f[2];
    #pragma unroll
    for (int mi = 0; mi < 2; mi++) {
        U4 u; u.q = *(const uint4*)(A3Lg + (((2 * w + mi) * 16 + l15) << 5) + quad * 8);
        a3f[mi] = u.v;
    }

    int pbase = blockIdx.x << 4;           // 16 points per block, batch-aligned
    int b = pbase >> 16;
    int n0 = pbase & 65535;
    const float4* xq = (const float4*)xh + ((size_t)b << 17);

    // zero NExq pad region (Wcat cols 137..159 are zero, but 0 x NaN = NaN)
    for (int j = t; j < 336; j += 256) NExq[j] = make_uint4(0u, 0u, 0u, 0u);

    // ---- phase A: gather all 256 Delta-rows (32B f32 each; 4MB/batch working
    // set -> L2-resident, proven R6: FETCH 254->40MB) ----
    {
        int pt = t >> 4, slot = t & 15;
        int srow = (slot < 15) ? slot + 1 : 1;     // slot 15 dups neighbor row 1
        int idx = nbr[(b << 20) | (srow << 16) | (n0 + pt)];
        float4 ga = xq[(u32)(idx << 1)], gb = xq[(u32)((idx << 1) + 1)];
        float4 ca = xq[(u32)((n0 + pt) << 1)], cb = xq[(u32)(((n0 + pt) << 1) + 1)];
        uint4 d;
        d.x = pack_rne(ga.x - ca.x, ga.y - ca.y);
        d.y = pack_rne(ga.z - ca.z, ga.w - ca.w);
        d.z = pack_rne(gb.x - cb.x, gb.y - cb.y);
        d.w = pack_rne(gb.z - cb.z, gb.w - cb.w);
        DXs[t] = d;
    }
    __syncthreads();

    S1(0, 0)
    __syncthreads();

    for (int p = 0; p < 16; p += 2) {
        S1(p + 1, 1)
        S2(p, 0)
        __syncthreads();
        if (p < 14) S1(p + 2, 0)
        S2(p + 1, 1)
        __syncthreads();
    }

    // ---- fused combine epilogue: out = Wcat @ [NE; x_bf16; 1; 0] ----
    if (t < 16) {
        const float4* xr = xq + ((u32)(n0 + t) << 1);
        float4 xa = xr[0], xb = xr[1];
        u32* dst = (u32*)NExq + t * 84 + 64;
        dst[0] = pack_rne(xa.x, xa.y);
        dst[1] = pack_rne(xa.z, xa.w);
        dst[2] = pack_rne(xb.x, xb.y);
        dst[3] = pack_rne(xb.z, xb.w);
        dst[4] = 0x3F80u;                  // the "1.0" slot (ch136)
    }
    __syncthreads();

    bf16x8 Wcf[2][5];
    #pragma unroll
    for (int mt = 0; mt < 2; mt++)
        #pragma unroll
        for (int kt = 0; kt < 5; kt++) {
            U4 u; u.q = *(const uint4*)(Wcat + (w * 32 + mt * 16 + l15) * 160 + kt * 32 + quad * 8);
            Wcf[mt][kt] = u.v;
        }
    f32x4 oa[2];
    oa[0] = (f32x4){0.f, 0.f, 0.f, 0.f};
    oa[1] = (f32x4){0.f, 0.f, 0.f, 0.f};
    #pragma unroll
    for (int kt = 0; kt < 5; ++kt) {
        U4 u; u.q = NExq[l15 * 21 + kt * 4 + quad];
        oa[0] = __builtin_amdgcn_mfma_f32_16x16x32_bf16(Wcf[0][kt], u.v, oa[0], 0, 0, 0);
        oa[1] = __builtin_amdgcn_mfma_f32_16x16x32_bf16(Wcf[1][kt], u.v, oa[1], 0, 0, 0);
    }
    #pragma unroll
    for (int mt = 0; mt < 2; ++mt) {
        int ob = w * 32 + mt * 16 + quad * 4;
        #pragma unroll
        for (int r = 0; r < 4; ++r)
            out[(((b << 7) + ob + r) << 16) + n0 + l15] = oa[mt][r];
    }
}

extern "C" void kernel_launch(void* const* d_in, const int* in_sizes, int n_in,
                              void* d_out, int out_size, void* d_ws, size_t ws_size,
                              hipStream_t stream) {
    const float* x   = (const float*)d_in[0];
    const int*   nbr = (const int*)d_in[1];
    const float* g1  = (const float*)d_in[2];
    const float* b1  = (const float*)d_in[3];
    const float* m1  = (const float*)d_in[4];
    const float* v1  = (const float*)d_in[5];
    const float* w1  = (const float*)d_in[6];
    const float* c1b = (const float*)d_in[7];
    const float* g2  = (const float*)d_in[8];
    const float* b2  = (const float*)d_in[9];
    const float* m2  = (const float*)d_in[10];
    const float* v2  = (const float*)d_in[11];
    const float* wA  = (const float*)d_in[12];
    const float* g3  = (const float*)d_in[13];
    const float* b3  = (const float*)d_in[14];
    const float* m3  = (const float*)d_in[15];
    const float* v3  = (const float*)d_in[16];
    const float* wB  = (const float*)d_in[17];
    const float* wf  = (const float*)d_in[18];
    const float* bfv = (const float*)d_in[19];

    u16*   A3L  = (u16*)((char*)d_ws + WS_A3L);
    u16*   wBh  = (u16*)((char*)d_ws + WS_WB);
    u16*   Wcat = (u16*)((char*)d_ws + WS_WCAT);
    float* xh   = (float*)((char*)d_ws + WS_XH);
    float* out  = (float*)d_out;

    prep_kernel<<<1, 256, 0, stream>>>(g1, b1, m1, v1, w1, c1b, g2, b2, m2, v2,
                                       wA, g3, b3, m3, v3, wB, wf, bfv, A3L, wBh, Wcat);
    xhat_kernel<<<512, 256, 0, stream>>>(x, xh);
    heavy_kernel<<<8192, 256, 0, stream>>>(xh, nbr, A3L, wBh, Wcat, out);
}

// Round 8
// 242.573 us; speedup vs baseline: 1.8699x; 1.0034x over previous
//
#include <hip/hip_runtime.h>
#include <hip/hip_bf16.h>

typedef unsigned short u16;
typedef unsigned int u32;
typedef short bf16x8 __attribute__((ext_vector_type(8)));
typedef float f32x4 __attribute__((ext_vector_type(4)));

#define EPSV 1e-5f
// ws byte layout
#define WS_A3L   0                       // 128*32 bf16 [A3 | c3 | 0...] = 8 KB
#define WS_WB    8192                    // 128*128 bf16 = 32 KB
#define WS_WCAT  40960                   // 128*160 bf16 [wf2 | A1 | bias | 0] = 40 KB
#define WS_XH    81920                   // 2*65536*8 f32 x-transpose = 4 MB

union U4 { uint4 q; bf16x8 v; };

__device__ __forceinline__ u16 f2bf(float f) {
    union { __hip_bfloat16 h; u16 u; } cv;
    cv.h = __float2bfloat16(f);
    return cv.u;
}
// RNE pack of two f32 into packed bf16 pair (lo = a, hi = b) — pure integer ops
__device__ __forceinline__ u32 pack_rne(float a, float b) {
    u32 ua = __float_as_uint(a), ub = __float_as_uint(b);
    ua = ua + 0x7FFFu + ((ua >> 16) & 1u);
    ub = ub + 0x7FFFu + ((ub >> 16) & 1u);
    return (ua >> 16) | (ub & 0xFFFF0000u);
}

// ---------------- prep: fold constants (fully parallel, LDS-staged) ----------------
__global__ __launch_bounds__(256) void prep_kernel(
    const float* g1, const float* b1, const float* m1, const float* v1,
    const float* w1, const float* c1b,
    const float* g2, const float* b2, const float* m2, const float* v2,
    const float* wA,
    const float* g3, const float* b3, const float* m3, const float* v3,
    const float* wB, const float* wf, const float* bfv,
    u16* A3L, u16* wBh, u16* Wc)
{
    __shared__ float wfL[16384];     // wf left half, 64 KB
    __shared__ float w1s[1024];
    __shared__ float c1s[128];
    __shared__ float s1[8], be1[8], s2[8], be2[8];
    __shared__ float w1fS[128][8];
    __shared__ float cbS[128];
    int t = threadIdx.x;

    for (int i = t; i < 16384; i += 256) wfL[i] = wf[((i >> 7) << 8) + (i & 127)];
    for (int i = t; i < 1024; i += 256) w1s[i] = w1[i];
    if (t < 128) c1s[t] = c1b[t];
    if (t < 8) {
        float s = g1[t] * rsqrtf(v1[t] + EPSV); s1[t] = s; be1[t] = b1[t] - m1[t] * s;
        float u = g2[t] * rsqrtf(v2[t] + EPSV); s2[t] = u; be2[t] = b2[t] - m2[t] * u;
    }
    __syncthreads();

    // fold wf_left @ [w1 | c1b]: thread (o, half) does 4 i's (+ cb on half 1)
    {
        int o = t >> 1, half = t & 1;
        float a0 = 0.f, a1 = 0.f, a2 = 0.f, a3 = 0.f, cb = 0.f;
        const float* wro = wfL + o * 128;
        int i0 = half * 4;
        for (int c = 0; c < 128; c++) {
            float f = wro[c];
            const float* wr = w1s + c * 8 + i0;
            a0 += f * wr[0]; a1 += f * wr[1]; a2 += f * wr[2]; a3 += f * wr[3];
            if (half) cb += f * c1s[c];
        }
        w1fS[o][i0] = a0; w1fS[o][i0 + 1] = a1; w1fS[o][i0 + 2] = a2; w1fS[o][i0 + 3] = a3;
        if (half) cbS[o] = cb;
    }
    __syncthreads();

    if (t < 128) {
        int o = t;
        float s3 = g3[o] * rsqrtf(v3[o] + EPSV);
        float be3 = b3[o] - m3[o] * s3;
        float csum = 0.f;
        #pragma unroll
        for (int i = 0; i < 8; i++) {
            float wv = wA[o * 8 + i];
            A3L[o * 32 + i] = f2bf(s3 * wv * s2[i] * s1[i]);
            csum += wv * be2[i];
        }
        A3L[o * 32 + 8] = f2bf(s3 * csum + be3);   // c3 folded as ones-channel
        for (int k = 9; k < 32; k++) A3L[o * 32 + k] = 0;

        float bs = bfv[o] + cbS[o];
        #pragma unroll
        for (int i = 0; i < 8; i++) {
            float w1f = w1fS[o][i];
            bs += w1f * be1[i];
            Wc[o * 160 + 128 + i] = f2bf(w1f * s1[i]);
        }
        Wc[o * 160 + 136] = f2bf(bs);
        for (int k = 137; k < 160; k++) Wc[o * 160 + k] = 0;
    }
    // Wcat wf2 block: 16384 elems, coalesced grid-stride
    for (int j = t; j < 16384; j += 256) {
        int o = j >> 7, c = j & 127;
        Wc[o * 160 + c] = f2bf(wf[o * 256 + 128 + c]);
    }
    // wB cast: 8192 packed u32, coalesced
    {
        u32* wbo = (u32*)wBh;
        for (int j = t; j < 8192; j += 256)
            wbo[j] = pack_rne(wB[2 * j], wB[2 * j + 1]);
    }
}

// ---------------- xhat: x transpose to [b][n][8ch] f32 rows (32B) ----------------
__global__ __launch_bounds__(256) void xhat_kernel(const float* __restrict__ x,
                                                   float* __restrict__ xh)
{
    int t = blockIdx.x * 256 + threadIdx.x;   // 131072 threads
    int b = t >> 16, n = t & 65535;
    float4 a, c;
    a.x = x[(((b << 3) + 0) << 16) | n];
    a.y = x[(((b << 3) + 1) << 16) | n];
    a.z = x[(((b << 3) + 2) << 16) | n];
    a.w = x[(((b << 3) + 3) << 16) | n];
    c.x = x[(((b << 3) + 4) << 16) | n];
    c.y = x[(((b << 3) + 5) << 16) | n];
    c.z = x[(((b << 3) + 6) << 16) | n];
    c.w = x[(((b << 3) + 7) << 16) | n];
    float4* o = (float4*)xh + ((size_t)t << 1);
    o[0] = a; o[1] = c;
}

// ---------------- heavy v9: v8 + 2-point phases (barriers 33 -> 10) ------------
// R7 PMC: MFMA floor 44us, VALU ~21us, stall ~53us across 33 block barriers
// (~10 MFMA between barriers). This round: Abuf = 4 x 4KB tiles (2 phase-bufs x
// 2 pts); each phase = {S1 x2 into other phase-buf || S2 x2 from current}, ONE
// barrier. 20 MFMA/barrier-interval; the two independent S2 shfl-reduce chains
// interleave (latency overlap). LDS 25.9KB -> still 6 blocks/CU. No numerics
// change vs R7 (which passed with cvtpk S1 pack).
#define S1(P, IDX)                                                            \
    {                                                                         \
        U4 bfr;                                                               \
        if (quad == 0)      bfr.q = DXs[((P) << 4) + l15];                    \
        else if (quad == 1) bfr.q = make_uint4(0x00003F80u, 0u, 0u, 0u);      \
        else                bfr.q = make_uint4(0u, 0u, 0u, 0u);               \
        f32x4 z0 = {0.f, 0.f, 0.f, 0.f}, z1 = {0.f, 0.f, 0.f, 0.f};           \
        z0 = __builtin_amdgcn_mfma_f32_16x16x32_bf16(a3f[0], bfr.v, z0, 0, 0, 0); \
        z1 = __builtin_amdgcn_mfma_f32_16x16x32_bf16(a3f[1], bfr.v, z1, 0, 0, 0); \
        u32 w00, w01, w10, w11;                                               \
        asm("v_cvt_pk_bf16_f32 %0, %1, %2" : "=v"(w00)                        \
            : "v"(fmaxf(z0[0], 0.f)), "v"(fmaxf(z0[1], 0.f)));                \
        asm("v_cvt_pk_bf16_f32 %0, %1, %2" : "=v"(w01)                        \
            : "v"(fmaxf(z0[2], 0.f)), "v"(fmaxf(z0[3], 0.f)));                \
        asm("v_cvt_pk_bf16_f32 %0, %1, %2" : "=v"(w10)                        \
            : "v"(fmaxf(z1[0], 0.f)), "v"(fmaxf(z1[1], 0.f)));                \
        asm("v_cvt_pk_bf16_f32 %0, %1, %2" : "=v"(w11)                        \
            : "v"(fmaxf(z1[2], 0.f)), "v"(fmaxf(z1[3], 0.f)));                \
        u32* ab = (u32*)Abuf + (IDX) * 1024 + (l15 << 6) + ((quad & 1) << 1); \
        int gA = ((w << 2) + (quad >> 1)) ^ (l15 & 7);                        \
        int gB = ((w << 2) + 2 + (quad >> 1)) ^ (l15 & 7);                    \
        *(uint2*)(ab + (gA << 2)) = make_uint2(w00, w01);                     \
        *(uint2*)(ab + (gB << 2)) = make_uint2(w10, w11);                     \
    }

#define S2(P, IDX)                                                            \
    {                                                                         \
        f32x4 acc0 = {0.f, 0.f, 0.f, 0.f}, acc1 = {0.f, 0.f, 0.f, 0.f};       \
        _Pragma("unroll")                                                     \
        for (int kt = 0; kt < 4; ++kt) {                                      \
            U4 a; a.q = ((const uint4*)Abuf)[(IDX) * 256 + (l15 << 4)         \
                                             + (((kt << 2) + quad) ^ (l15 & 7))]; \
            acc0 = __builtin_amdgcn_mfma_f32_16x16x32_bf16(a.v, wBf[0][kt], acc0, 0, 0, 0); \
            acc1 = __builtin_amdgcn_mfma_f32_16x16x32_bf16(a.v, wBf[1][kt], acc1, 0, 0, 0); \
        }                                                                     \
        float m0 = fmaxf(fmaxf(fmaxf(acc0[0], acc0[1]), acc0[2]), acc0[3]);   \
        float m1 = fmaxf(fmaxf(fmaxf(acc1[0], acc1[1]), acc1[2]), acc1[3]);   \
        m0 = fmaxf(m0, __shfl_xor(m0, 16, 64));                               \
        m0 = fmaxf(m0, __shfl_xor(m0, 32, 64));                               \
        m1 = fmaxf(m1, __shfl_xor(m1, 16, 64));                               \
        m1 = fmaxf(m1, __shfl_xor(m1, 32, 64));                               \
        if (l < 32)                                                           \
            NEu16[(P) * 168 + (w << 5) + l] =                                 \
                (u16)((__float_as_uint((quad == 0) ? m0 : m1) + 0x8000u) >> 16); \
    }

__global__ __launch_bounds__(256, 6) void heavy_kernel(
    const float* __restrict__ xh, const int* __restrict__ nbr,
    const u16* __restrict__ A3Lg, const u16* __restrict__ wBh,
    const u16* __restrict__ Wcat, float* __restrict__ out)
{
    __shared__ uint4 DXs[256];             // [row] dx bf16x8, 4KB
    __shared__ uint4 Abuf[4][16][16];      // 2 phase-bufs x 2 pts, 16KB
    __shared__ uint4 NExq[16 * 21];        // [pt][NE(128)|x(8)|1|0...], 5.25KB
    u16* NEu16 = (u16*)NExq;
    int t = threadIdx.x;
    int w = t >> 6, l = t & 63;
    int quad = l >> 4, l15 = l & 15;

    // persistent wB^T B-fragments (stage-2), 32 regs
    bf16x8 wBf[2][4];
    #pragma unroll
    for (int j = 0; j < 2; j++)
        #pragma unroll
        for (int kt = 0; kt < 4; kt++) {
            U4 u; u.q = *(const uint4*)(wBh + (w * 32 + j * 16 + l15) * 128 + kt * 32 + quad * 8);
            wBf[j][kt] = u.v;
        }
    // persistent stage-1 A-frags: A3L rows for o-blocks 32w+16mi, 16 regs
    bf16x8 a3f[2];
    #pragma unroll
    for (int mi = 0; mi < 2; mi++) {
        U4 u; u.q = *(const uint4*)(A3Lg + (((2 * w + mi) * 16 + l15) << 5) + quad * 8);
        a3f[mi] = u.v;
    }

    int pbase = blockIdx.x << 4;           // 16 points per block, batch-aligned
    int b = pbase >> 16;
    int n0 = pbase & 65535;
    const float4* xq = (const float4*)xh + ((size_t)b << 17);

    // zero NExq pad region (Wcat cols 137..159 are zero, but 0 x NaN = NaN)
    for (int j = t; j < 336; j += 256) NExq[j] = make_uint4(0u, 0u, 0u, 0u);

    // ---- phase A: gather all 256 Delta-rows (32B f32 each; 4MB/batch working
    // set -> L2-resident, proven R6: FETCH 254->40MB) ----
    {
        int pt = t >> 4, slot = t & 15;
        int srow = (slot < 15) ? slot + 1 : 1;     // slot 15 dups neighbor row 1
        int idx = nbr[(b << 20) | (srow << 16) | (n0 + pt)];
        float4 ga = xq[(u32)(idx << 1)], gb = xq[(u32)((idx << 1) + 1)];
        float4 ca = xq[(u32)((n0 + pt) << 1)], cb = xq[(u32)(((n0 + pt) << 1) + 1)];
        uint4 d;
        d.x = pack_rne(ga.x - ca.x, ga.y - ca.y);
        d.y = pack_rne(ga.z - ca.z, ga.w - ca.w);
        d.z = pack_rne(gb.x - cb.x, gb.y - cb.y);
        d.w = pack_rne(gb.z - cb.z, gb.w - cb.w);
        DXs[t] = d;
    }
    __syncthreads();

    // prologue: produce pts 0,1 into phase-buf 0 (tiles 0,1)
    S1(0, 0)
    S1(1, 1)
    __syncthreads();

    // 8 phases, 1 barrier each: S1 next pair into other buf || S2 current pair
    for (int k = 0; k < 8; k += 2) {
        S1(2 * k + 2, 2)                   // -> phase-buf 1
        S1(2 * k + 3, 3)
        S2(2 * k, 0)                       // <- phase-buf 0
        S2(2 * k + 1, 1)
        __syncthreads();
        if (k < 6) {
            S1(2 * k + 4, 0)               // -> phase-buf 0
            S1(2 * k + 5, 1)
        }
        S2(2 * k + 2, 2)                   // <- phase-buf 1
        S2(2 * k + 3, 3)
        __syncthreads();
    }

    // ---- fused combine epilogue: out = Wcat @ [NE; x_bf16; 1; 0] ----
    if (t < 16) {
        const float4* xr = xq + ((u32)(n0 + t) << 1);
        float4 xa = xr[0], xb = xr[1];
        u32* dst = (u32*)NExq + t * 84 + 64;
        dst[0] = pack_rne(xa.x, xa.y);
        dst[1] = pack_rne(xa.z, xa.w);
        dst[2] = pack_rne(xb.x, xb.y);
        dst[3] = pack_rne(xb.z, xb.w);
        dst[4] = 0x3F80u;                  // the "1.0" slot (ch136)
    }
    __syncthreads();

    bf16x8 Wcf[2][5];
    #pragma unroll
    for (int mt = 0; mt < 2; mt++)
        #pragma unroll
        for (int kt = 0; kt < 5; kt++) {
            U4 u; u.q = *(const uint4*)(Wcat + (w * 32 + mt * 16 + l15) * 160 + kt * 32 + quad * 8);
            Wcf[mt][kt] = u.v;
        }
    f32x4 oa[2];
    oa[0] = (f32x4){0.f, 0.f, 0.f, 0.f};
    oa[1] = (f32x4){0.f, 0.f, 0.f, 0.f};
    #pragma unroll
    for (int kt = 0; kt < 5; ++kt) {
        U4 u; u.q = NExq[l15 * 21 + kt * 4 + quad];
        oa[0] = __builtin_amdgcn_mfma_f32_16x16x32_bf16(Wcf[0][kt], u.v, oa[0], 0, 0, 0);
        oa[1] = __builtin_amdgcn_mfma_f32_16x16x32_bf16(Wcf[1][kt], u.v, oa[1], 0, 0, 0);
    }
    #pragma unroll
    for (int mt = 0; mt < 2; ++mt) {
        int ob = w * 32 + mt * 16 + quad * 4;
        #pragma unroll
        for (int r = 0; r < 4; ++r)
            out[(((b << 7) + ob + r) << 16) + n0 + l15] = oa[mt][r];
    }
}

extern "C" void kernel_launch(void* const* d_in, const int* in_sizes, int n_in,
                              void* d_out, int out_size, void* d_ws, size_t ws_size,
                              hipStream_t stream) {
    const float* x   = (const float*)d_in[0];
    const int*   nbr = (const int*)d_in[1];
    const float* g1  = (const float*)d_in[2];
    const float* b1  = (const float*)d_in[3];
    const float* m1  = (const float*)d_in[4];
    const float* v1  = (const float*)d_in[5];
    const float* w1  = (const float*)d_in[6];
    const float* c1b = (const float*)d_in[7];
    const float* g2  = (const float*)d_in[8];
    const float* b2  = (const float*)d_in[9];
    const float* m2  = (const float*)d_in[10];
    const float* v2  = (const float*)d_in[11];
    const float* wA  = (const float*)d_in[12];
    const float* g3  = (const float*)d_in[13];
    const float* b3  = (const float*)d_in[14];
    const float* m3  = (const float*)d_in[15];
    const float* v3  = (const float*)d_in[16];
    const float* wB  = (const float*)d_in[17];
    const float* wf  = (const float*)d_in[18];
    const float* bfv = (const float*)d_in[19];

    u16*   A3L  = (u16*)((char*)d_ws + WS_A3L);
    u16*   wBh  = (u16*)((char*)d_ws + WS_WB);
    u16*   Wcat = (u16*)((char*)d_ws + WS_WCAT);
    float* xh   = (float*)((char*)d_ws + WS_XH);
    float* out  = (float*)d_out;

    prep_kernel<<<1, 256, 0, stream>>>(g1, b1, m1, v1, w1, c1b, g2, b2, m2, v2,
                                       wA, g3, b3, m3, v3, wB, wf, bfv, A3L, wBh, Wcat);
    xhat_kernel<<<512, 256, 0, stream>>>(x, xh);
    heavy_kernel<<<8192, 256, 0, stream>>>(xh, nbr, A3L, wBh, Wcat, out);
}

// Round 9
// 221.142 us; speedup vs baseline: 2.0511x; 1.0969x over previous
//
#include <hip/hip_runtime.h>
#include <hip/hip_bf16.h>

typedef unsigned short u16;
typedef unsigned int u32;
typedef short bf16x8 __attribute__((ext_vector_type(8)));
typedef float f32x4 __attribute__((ext_vector_type(4)));
typedef float f32x16 __attribute__((ext_vector_type(16)));

#define EPSV 1e-5f
// ws byte layout
#define WS_A3L   0                       // 128*32 bf16 [A3 | c3 | 0...] = 8 KB
#define WS_WB    8192                    // 128*128 bf16 = 32 KB
#define WS_WCAT  40960                   // 128*160 bf16 [wf2 | A1 | bias | 0] = 40 KB
#define WS_XH    81920                   // 2*65536*8 f32 x-transpose = 4 MB

union U4 { uint4 q; bf16x8 v; };

__device__ __forceinline__ u16 f2bf(float f) {
    union { __hip_bfloat16 h; u16 u; } cv;
    cv.h = __float2bfloat16(f);
    return cv.u;
}
// RNE pack of two f32 into packed bf16 pair (lo = a, hi = b) — pure integer ops
__device__ __forceinline__ u32 pack_rne(float a, float b) {
    u32 ua = __float_as_uint(a), ub = __float_as_uint(b);
    ua = ua + 0x7FFFu + ((ua >> 16) & 1u);
    ub = ub + 0x7FFFu + ((ub >> 16) & 1u);
    return (ua >> 16) | (ub & 0xFFFF0000u);
}

// ---------------- setup: xhat (blocks 0..511) + prep (blocks 512..543) ----------
__global__ __launch_bounds__(256) void setup_kernel(
    const float* __restrict__ x,
    const float* g1, const float* b1, const float* m1, const float* v1,
    const float* w1, const float* c1b,
    const float* g2, const float* b2, const float* m2, const float* v2,
    const float* wA,
    const float* g3, const float* b3, const float* m3, const float* v3,
    const float* wB, const float* wf, const float* bfv,
    float* __restrict__ xh, u16* A3L, u16* wBh, u16* Wc)
{
    __shared__ float w1s[1024];
    __shared__ float c1s[128];
    __shared__ float s1[8], be1[8], s2[8], be2[8];
    __shared__ float w1fS[128][8];
    __shared__ float cbS[128];
    int bid = blockIdx.x, t = threadIdx.x;

    if (bid < 512) {
        // xhat: x transpose to [b][n][8ch] f32 rows (32B)
        int tg = (bid << 8) + t;
        int b = tg >> 16, n = tg & 65535;
        float4 a, c;
        a.x = x[(((b << 3) + 0) << 16) | n];
        a.y = x[(((b << 3) + 1) << 16) | n];
        a.z = x[(((b << 3) + 2) << 16) | n];
        a.w = x[(((b << 3) + 3) << 16) | n];
        c.x = x[(((b << 3) + 4) << 16) | n];
        c.y = x[(((b << 3) + 5) << 16) | n];
        c.z = x[(((b << 3) + 6) << 16) | n];
        c.w = x[(((b << 3) + 7) << 16) | n];
        float4* o = (float4*)xh + ((size_t)tg << 1);
        o[0] = a; o[1] = c;
        return;
    }
    int rb = bid - 512;                 // 0..31
    // distributed big copies (32 blocks)
    for (int j = (rb << 8) + t; j < 16384; j += 8192) {
        int o = j >> 7, c = j & 127;
        Wc[o * 160 + c] = f2bf(wf[o * 256 + 128 + c]);
    }
    {
        int j = (rb << 8) + t;          // 8192 packed u32 over 8192 threads
        ((u32*)wBh)[j] = pack_rne(wB[2 * j], wB[2 * j + 1]);
    }
    if (rb) return;

    // ---- fold (single block) ----
    for (int i = t; i < 1024; i += 256) w1s[i] = w1[i];
    if (t < 128) c1s[t] = c1b[t];
    if (t < 8) {
        float s = g1[t] * rsqrtf(v1[t] + EPSV); s1[t] = s; be1[t] = b1[t] - m1[t] * s;
        float u = g2[t] * rsqrtf(v2[t] + EPSV); s2[t] = u; be2[t] = b2[t] - m2[t] * u;
    }
    __syncthreads();

    // fold wf_left @ [w1 | c1b]: thread (o, half) does 4 i's (+ cb on half 1)
    {
        int o = t >> 1, half = t & 1;
        float a0 = 0.f, a1 = 0.f, a2 = 0.f, a3 = 0.f, cb = 0.f;
        const float* wro = wf + o * 256;     // left half cols 0..127 (L2-hot)
        int i0 = half * 4;
        for (int c = 0; c < 128; c++) {
            float f = wro[c];
            const float* wr = w1s + c * 8 + i0;
            a0 += f * wr[0]; a1 += f * wr[1]; a2 += f * wr[2]; a3 += f * wr[3];
            if (half) cb += f * c1s[c];
        }
        w1fS[o][i0] = a0; w1fS[o][i0 + 1] = a1; w1fS[o][i0 + 2] = a2; w1fS[o][i0 + 3] = a3;
        if (half) cbS[o] = cb;
    }
    __syncthreads();

    if (t < 128) {
        int o = t;
        float s3 = g3[o] * rsqrtf(v3[o] + EPSV);
        float be3 = b3[o] - m3[o] * s3;
        float csum = 0.f;
        #pragma unroll
        for (int i = 0; i < 8; i++) {
            float wv = wA[o * 8 + i];
            A3L[o * 32 + i] = f2bf(s3 * wv * s2[i] * s1[i]);
            csum += wv * be2[i];
        }
        A3L[o * 32 + 8] = f2bf(s3 * csum + be3);   // c3 folded as ones-channel
        for (int k = 9; k < 32; k++) A3L[o * 32 + k] = 0;

        float bs = bfv[o] + cbS[o];
        #pragma unroll
        for (int i = 0; i < 8; i++) {
            float w1f = w1fS[o][i];
            bs += w1f * be1[i];
            Wc[o * 160 + 128 + i] = f2bf(w1f * s1[i]);
        }
        Wc[o * 160 + 136] = f2bf(bs);
        for (int k = 137; k < 160; k++) Wc[o * 160 + k] = 0;
    }
}

// ---------------- heavy v10: 32x32x16 MFMA point-pair restructure --------------
// R8 falsified barrier theory (33->12 barriers, identical 115us). New theory:
// aggregate pipe pressure (MFMA bursts + LDS port + chains). 32x32x16 shape on
// point-PAIRS (32 slots = 2pts x 16): S1 = 1 MFMA/pair/wave (vs 4; K=16 wastes
// 7/16 not 23/32), S2 = 8 (vs 16), shfl 2/pair (vs 8), all-64-lane NE writes.
// MFMA/block 680 -> 328; pipe floor 105K -> 81K cycles.
// Fragment maps (row=lane%M, k=(lane/M)*8+j, same convention as the proven
// 16x16x32 path; C: col=lane&31, row=(reg&3)+8*(reg>>2)+4*(lane>>5) [m74/m101]):
//  S1: A=A3L[row=32w+l31][k=hi*8+j]; B=DX (lanes<32: dx row of slot l31;
//      lanes>=32: const [1,0..] = ones-channel k=8 multiplying folded c3).
//      C[crow=ch][col=slot] -> relu+cvtpk pairs -> Abuf[slot][granule 4w+gi ^
//      (slot&7)] at u32 (2hi..2hi+1) — each (granule,u32) written exactly once.
//  S2: A=Abuf[row=slot=l31][k-granule (2kt+hi)^(l31&7)]; B=wBh[n=32w+l31][k];
//      C[row=slot][col=ch]. pt_even = regs 0..7, pt_odd = 8..15 (both hi
//      halves hold disjoint slots -> one xor-32 shfl each). Bank-audited
//      conflict-free on both write and read.
#define S1(P, BUF)                                                            \
    {                                                                         \
        U4 bfr;                                                               \
        if (hi == 0) bfr.q = DXs[((P) << 5) + l31];                           \
        else         bfr.q = make_uint4(0x00003F80u, 0u, 0u, 0u);             \
        f32x16 z = {};                                                        \
        z = __builtin_amdgcn_mfma_f32_32x32x16_bf16(a3f, bfr.v, z, 0, 0, 0);  \
        u32* ab = (u32*)Abuf + (BUF) * 2048 + (l31 << 6) + (hi << 1);         \
        _Pragma("unroll")                                                     \
        for (int gi = 0; gi < 4; gi++) {                                      \
            u32 plo, phi;                                                     \
            asm("v_cvt_pk_bf16_f32 %0, %1, %2" : "=v"(plo)                    \
                : "v"(fmaxf(z[4 * gi + 0], 0.f)), "v"(fmaxf(z[4 * gi + 1], 0.f))); \
            asm("v_cvt_pk_bf16_f32 %0, %1, %2" : "=v"(phi)                    \
                : "v"(fmaxf(z[4 * gi + 2], 0.f)), "v"(fmaxf(z[4 * gi + 3], 0.f))); \
            int gsw = (((w << 2) + gi) ^ (l31 & 7)) << 2;                     \
            *(uint2*)(ab + gsw) = make_uint2(plo, phi);                       \
        }                                                                     \
    }

#define S2(P, BUF)                                                            \
    {                                                                         \
        f32x16 acc = {};                                                      \
        _Pragma("unroll")                                                     \
        for (int kt = 0; kt < 8; ++kt) {                                      \
            U4 a; a.q = Abuf[BUF][l31][((kt << 1) + hi) ^ (l31 & 7)];         \
            acc = __builtin_amdgcn_mfma_f32_32x32x16_bf16(a.v, wBf[kt], acc, 0, 0, 0); \
        }                                                                     \
        float me = fmaxf(fmaxf(fmaxf(acc[0], acc[1]), fmaxf(acc[2], acc[3])), \
                         fmaxf(fmaxf(acc[4], acc[5]), fmaxf(acc[6], acc[7]))); \
        float mo = fmaxf(fmaxf(fmaxf(acc[8], acc[9]), fmaxf(acc[10], acc[11])), \
                         fmaxf(fmaxf(acc[12], acc[13]), fmaxf(acc[14], acc[15]))); \
        me = fmaxf(me, __shfl_xor(me, 32, 64));                               \
        mo = fmaxf(mo, __shfl_xor(mo, 32, 64));                               \
        float mv = hi ? mo : me;                                              \
        NEu16[(((P) << 1) + hi) * 168 + (w << 5) + l31] =                     \
            (u16)((__float_as_uint(mv) + 0x8000u) >> 16);                     \
    }

__global__ __launch_bounds__(256, 6) void heavy_kernel(
    const float* __restrict__ xh, const int* __restrict__ nbr,
    const u16* __restrict__ A3Lg, const u16* __restrict__ wBh,
    const u16* __restrict__ Wcat, float* __restrict__ out)
{
    __shared__ uint4 DXs[256];             // [row] dx bf16x8, 4KB
    __shared__ uint4 Abuf[2][32][16];      // z dbuf [buf][slot32][granule^swz], 16KB
    __shared__ uint4 NExq[16 * 21];        // [pt][NE(128)|x(8)|1|0...], 5.25KB
    u16* NEu16 = (u16*)NExq;
    int t = threadIdx.x;
    int w = t >> 6, l = t & 63;
    int l31 = l & 31, hi = l >> 5;
    int quad = l >> 4, l15 = l & 15;       // epilogue (16x16 path)

    // persistent wB^T B-frags (32x32x16): B[col=32w+l31][k=kt*16+hi*8+j], 32 regs
    bf16x8 wBf[8];
    #pragma unroll
    for (int kt = 0; kt < 8; kt++) {
        U4 u; u.q = *(const uint4*)(wBh + (w * 32 + l31) * 128 + kt * 16 + hi * 8);
        wBf[kt] = u.v;
    }
    // persistent S1 A-frag: A3L[row=32w+l31][k=hi*8+j], 4 regs
    bf16x8 a3f;
    {
        U4 u; u.q = *(const uint4*)(A3Lg + ((w * 32 + l31) << 5) + hi * 8);
        a3f = u.v;
    }

    int pbase = blockIdx.x << 4;           // 16 points per block, batch-aligned
    int b = pbase >> 16;
    int n0 = pbase & 65535;
    const float4* xq = (const float4*)xh + ((size_t)b << 17);

    // zero NExq pad region (Wcat cols 137..159 are zero, but 0 x NaN = NaN)
    for (int j = t; j < 336; j += 256) NExq[j] = make_uint4(0u, 0u, 0u, 0u);

    // ---- phase A: gather all 256 Delta-rows (32B f32 each; 4MB/batch working
    // set -> L2-resident, proven R6: FETCH 254->40MB) ----
    {
        int pt = t >> 4, slot = t & 15;
        int srow = (slot < 15) ? slot + 1 : 1;     // slot 15 dups neighbor row 1
        int idx = nbr[(b << 20) | (srow << 16) | (n0 + pt)];
        float4 ga = xq[(u32)(idx << 1)], gb = xq[(u32)((idx << 1) + 1)];
        float4 ca = xq[(u32)((n0 + pt) << 1)], cb = xq[(u32)(((n0 + pt) << 1) + 1)];
        uint4 d;
        d.x = pack_rne(ga.x - ca.x, ga.y - ca.y);
        d.y = pack_rne(ga.z - ca.z, ga.w - ca.w);
        d.z = pack_rne(gb.x - cb.x, gb.y - cb.y);
        d.w = pack_rne(gb.z - cb.z, gb.w - cb.w);
        DXs[t] = d;
    }
    __syncthreads();

    // 8 point-pairs, double-buffered: S1(next pair) || S2(current pair)
    S1(0, 0)
    __syncthreads();
    for (int p = 0; p < 8; ++p) {
        if (p < 7) S1(p + 1, (p + 1) & 1)
        S2(p, p & 1)
        __syncthreads();
    }

    // ---- fused combine epilogue: out = Wcat @ [NE; x_bf16; 1; 0] ----
    if (t < 16) {
        const float4* xr = xq + ((u32)(n0 + t) << 1);
        float4 xa = xr[0], xb = xr[1];
        u32* dst = (u32*)NExq + t * 84 + 64;
        dst[0] = pack_rne(xa.x, xa.y);
        dst[1] = pack_rne(xa.z, xa.w);
        dst[2] = pack_rne(xb.x, xb.y);
        dst[3] = pack_rne(xb.z, xb.w);
        dst[4] = 0x3F80u;                  // the "1.0" slot (ch136)
    }
    __syncthreads();

    bf16x8 Wcf[2][5];
    #pragma unroll
    for (int mt = 0; mt < 2; mt++)
        #pragma unroll
        for (int kt = 0; kt < 5; kt++) {
            U4 u; u.q = *(const uint4*)(Wcat + (w * 32 + mt * 16 + l15) * 160 + kt * 32 + quad * 8);
            Wcf[mt][kt] = u.v;
        }
    f32x4 oa[2];
    oa[0] = (f32x4){0.f, 0.f, 0.f, 0.f};
    oa[1] = (f32x4){0.f, 0.f, 0.f, 0.f};
    #pragma unroll
    for (int kt = 0; kt < 5; ++kt) {
        U4 u; u.q = NExq[l15 * 21 + kt * 4 + quad];
        oa[0] = __builtin_amdgcn_mfma_f32_16x16x32_bf16(Wcf[0][kt], u.v, oa[0], 0, 0, 0);
        oa[1] = __builtin_amdgcn_mfma_f32_16x16x32_bf16(Wcf[1][kt], u.v, oa[1], 0, 0, 0);
    }
    #pragma unroll
    for (int mt = 0; mt < 2; ++mt) {
        int ob = w * 32 + mt * 16 + quad * 4;
        #pragma unroll
        for (int r = 0; r < 4; ++r)
            out[(((b << 7) + ob + r) << 16) + n0 + l15] = oa[mt][r];
    }
}

extern "C" void kernel_launch(void* const* d_in, const int* in_sizes, int n_in,
                              void* d_out, int out_size, void* d_ws, size_t ws_size,
                              hipStream_t stream) {
    const float* x   = (const float*)d_in[0];
    const int*   nbr = (const int*)d_in[1];
    const float* g1  = (const float*)d_in[2];
    const float* b1  = (const float*)d_in[3];
    const float* m1  = (const float*)d_in[4];
    const float* v1  = (const float*)d_in[5];
    const float* w1  = (const float*)d_in[6];
    const float* c1b = (const float*)d_in[7];
    const float* g2  = (const float*)d_in[8];
    const float* b2  = (const float*)d_in[9];
    const float* m2  = (const float*)d_in[10];
    const float* v2  = (const float*)d_in[11];
    const float* wA  = (const float*)d_in[12];
    const float* g3  = (const float*)d_in[13];
    const float* b3  = (const float*)d_in[14];
    const float* m3  = (const float*)d_in[15];
    const float* v3  = (const float*)d_in[16];
    const float* wB  = (const float*)d_in[17];
    const float* wf  = (const float*)d_in[18];
    const float* bfv = (const float*)d_in[19];

    u16*   A3L  = (u16*)((char*)d_ws + WS_A3L);
    u16*   wBh  = (u16*)((char*)d_ws + WS_WB);
    u16*   Wcat = (u16*)((char*)d_ws + WS_WCAT);
    float* xh   = (float*)((char*)d_ws + WS_XH);
    float* out  = (float*)d_out;

    setup_kernel<<<544, 256, 0, stream>>>(x, g1, b1, m1, v1, w1, c1b,
                                          g2, b2, m2, v2, wA, g3, b3, m3, v3,
                                          wB, wf, bfv, xh, A3L, wBh, Wcat);
    heavy_kernel<<<8192, 256, 0, stream>>>(xh, nbr, A3L, wBh, Wcat, out);
}